// Round 8
// baseline (128.808 us; speedup 1.0000x reference)
//
#include <hip/hip_runtime.h>

#define B_    8
#define CIN_  64
#define COUT_ 64
#define H_    256
#define W_    256
#define HW_   65536

typedef __attribute__((ext_vector_type(8)))  short short8;    // 8 bf16 = 4 VGPRs
typedef __attribute__((ext_vector_type(16))) float f32x16;

static __device__ __forceinline__ unsigned short f2bf(float f) {
    union { float f; unsigned u; } v; v.f = f;
    unsigned r = (v.u + 0x7FFFu + ((v.u >> 16) & 1u)) >> 16;  // RNE
    return (unsigned short)r;
}

// async global->LDS, 16B per lane. LDS dest = wave-uniform base + lane*16.
static __device__ __forceinline__ void gload16(void* lds, const void* g) {
    __builtin_amdgcn_global_load_lds(
        (const __attribute__((address_space(1))) unsigned int*)g,
        (__attribute__((address_space(3))) unsigned int*)lds, 16, 0, 0);
}

// inline-asm barrier: also a compiler memory fence.
static __device__ __forceinline__ void bar() {
    asm volatile("s_barrier" ::: "memory");
}
static __device__ __forceinline__ void vm0() {
    asm volatile("s_waitcnt vmcnt(0)" ::: "memory");
}

// ws layout (bytes):
//   [0,       589824)  aggb3 [B][q(4)][tap(9)][ch(2)][co(64)][8ci] bf16
//   [589824,  589952)  zero pad (128 B)
#define WS_PAD_OFF 589824

// ---------------------------------------------------------------------------
// Kernel 1: aggregate weights -> bf16, layout aggb3[b][q][tap][ch][co][8ci]
// (q = ci/16, ch = (ci>>3)&1) + zero pad.
// ---------------------------------------------------------------------------
__global__ __launch_bounds__(256) void prep_weights_kernel(
    const float* __restrict__ att,     // [B][10]
    const float* __restrict__ weight,  // [COUT][CIN][9]
    const float* __restrict__ tb, const float* __restrict__ tq,
    const float* __restrict__ tn, const float* __restrict__ tx,
    const float* __restrict__ mb, const float* __restrict__ mq,
    const float* __restrict__ mn, const float* __restrict__ mx,
    unsigned short* __restrict__ aggb)
{
    int idx = blockIdx.x * 256 + threadIdx.x;
    if (idx < 64) aggb[294912 + idx] = 0;          // zero pad region (128 B)
    if (idx >= B_ * 9 * COUT_ * CIN_) return;
    int b    = idx / (9 * COUT_ * CIN_);
    int rem  = idx - b * (9 * COUT_ * CIN_);
    int tap  = rem / (COUT_ * CIN_);
    int rem2 = rem & (COUT_ * CIN_ - 1);
    int co   = rem2 >> 6;
    int ci   = rem2 & 63;

    int r  = (co * CIN_ + ci) * 9 + tap;   // [co][ci][kh][kw]
    int cc = co * CIN_ + ci;

    float a0 = att[b * 10 + 0];
    float a1 = att[b * 10 + 1];
    float a2 = att[b * 10 + 2];
    float val = weight[r]
              + tb[r] * mb[cc] * a1
              + tq[r] * mq[cc] * a2
              + (tn[r] * mn[cc] + tx[r] * mx[cc]) * a0;
    int q  = ci >> 4;
    int ch = (ci >> 3) & 1;
    int o  = ci & 7;
    aggb[((((b * 4 + q) * 9 + tap) * 2 + ch) * 64 + co) * 8 + o] = f2bf(val);
}

// ---------------------------------------------------------------------------
// Kernel 2 (FUSED): implicit-GEMM conv reading fp32 NCHW x directly.
// Block: 512 thr = 8 waves. Tile: 64 cout x (8 rows x 64 cols), one batch.
// 4 phases x 16 ci. Per phase:
//   1) global_load_lds stages fp32 x tile F[ci16][row10][px72] (coalesced:
//      each 16B chunk = 4 px of one ci; rows start at x0-4 for alignment;
//      OOB chunks -> zero pad) and bf16 weights Wd (linear, L2/L3-hot).
//   2) convert pass: F -> Xb bf16, slot stride 40 B (40*s mod 128 covers all
//      sixteen 8B residues -> ds_read_b128 conflict-free), chunk-XOR lk^(s&1).
//   3) compute: 9 taps x (2 A + 2 B ds_read_b128 -> 4 MFMA 32x32x16).
// Pipeline: issue(p+1) before compute(p); vmcnt(0) lands during compute.
// LDS 137344 B -> 1 block/CU (8 waves = 2/SIMD).
// ---------------------------------------------------------------------------
__global__ __launch_bounds__(512, 2) void conv_kernel(
    const float* __restrict__ x,            // [B][CIN][H][W] fp32
    const unsigned char* __restrict__ wsb,  // d_ws base (aggb3 + zpad)
    const float* __restrict__ bias,         // [COUT]
    float* __restrict__ out)                // [B][COUT][H][W] fp32
{
    __shared__ __align__(16) float          F[16 * 10 * 72];   // 46080 B
    __shared__ __align__(16) unsigned short Xb[2][680 * 20];   // 2 x 27200 B
    __shared__ __align__(16) unsigned short Wd[2][9216];       // 2 x 18432 B

    const int t = threadIdx.x;

    // XCD swizzle: 1024 blocks, xcd = bid&7 = batch; rt-major within XCD.
    int bid = blockIdx.x;
    int bz  = bid & 7;            // batch
    int idx = bid >> 3;           // 0..127
    int ct  = idx >> 5;           // 0..3  col tile
    int rt  = idx & 31;           // 0..31 row tile
    const int x0 = ct * 64;
    const int y0 = rt * 8;

    const int l  = t & 63;
    const int w  = t >> 6;        // wave 0..7 -> output row
    const int lp = l & 31;        // pixel / co lane
    const int lk = l >> 5;        // k-half

    const unsigned char* xB   = (const unsigned char*)x + ((size_t)bz << 24);
    const unsigned char* wbB  = wsb + (size_t)bz * 73728;
    const unsigned char* zpad = wsb + WS_PAD_OFF;

    // ---- F staging precompute: j = i*512+t < 2880; ci=j/180, rr, chunk ----
    int  fci[6], foff[6];
    bool fval[6];
#pragma unroll
    for (int i = 0; i < 6; ++i) {
        int j   = i * 512 + t;
        int ci  = j / 180;
        int r   = j - ci * 180;
        int rr  = r / 18;
        int chk = r - rr * 18;
        int gy  = y0 + rr - 1;
        int gx  = x0 - 4 + chk * 4;
        fci[i]  = ci;
        foff[i] = (gy * W_ + gx) * 4;
        fval[i] = ((unsigned)gy < (unsigned)H_) && ((unsigned)gx < (unsigned)W_);
    }

    auto issue_f = [&](int cb) {
#pragma unroll
        for (int i = 0; i < 6; ++i) {
            if (i < 5 || t < 320) {    // 2880 transfers; waves 0-4 on last iter
                const unsigned char* src = fval[i]
                    ? xB + (((size_t)(cb + fci[i])) << 18) + foff[i]
                    : zpad;
                gload16((char*)F + (i * 512 + t) * 16, src);
            }
        }
    };
    auto issue_w = [&](int q) {        // 1152 x 16B, linear both sides
        const unsigned char* src = wbB + q * 18432;
        char* dst = (char*)Wd[q & 1];
        gload16(dst + t * 16,        src + t * 16);
        gload16(dst + 8192 + t * 16, src + (8192 + t * 16));
        if (t < 128)
            gload16(dst + 16384 + t * 16, src + (16384 + t * 16));
    };

    // ---- convert: F (fp32) -> dst (bf16, 40B-slot, chunk-XOR) ----
    auto convert = [&](unsigned short* dst) {
#pragma unroll
        for (int i = 0; i < 11; ++i) {
            int wd = i * 512 + t;
            if (wd < 5440) {
                int k   = wd / 680;            // ci-pair 0..7
                int s   = wd - k * 680;        // slot = row*68+col
                int row = s / 68;
                int col = s - row * 68;
                int fi  = (2 * k) * 720 + row * 72 + col + 3;
                unsigned pk = (unsigned)f2bf(F[fi])
                            | ((unsigned)f2bf(F[fi + 720]) << 16);
                int byteo = s * 40 + (((k >> 2) ^ (s & 1)) << 4) + ((k & 3) << 2);
                *(unsigned*)((char*)dst + byteo) = pk;
            }
        }
    };

    f32x16 acc[2][2];             // [co-group][pixel-group]
#pragma unroll
    for (int i = 0; i < 16; ++i) {
        acc[0][0][i] = 0.f; acc[0][1][i] = 0.f;
        acc[1][0][i] = 0.f; acc[1][1][i] = 0.f;
    }

    auto compute = [&](const unsigned short* buf, const unsigned short* wdq) {
        const char* Ab = (const char*)wdq + lk * 1024 + lp * 16;
        const char* Bb = (const char*)buf;
        __builtin_amdgcn_s_setprio(1);
#pragma unroll
        for (int tap = 0; tap < 9; ++tap) {
            const int kh = tap / 3;
            const int kw = tap - kh * 3;
            short8 a0 = *(const short8*)(Ab + tap * 2048);
            short8 a1 = *(const short8*)(Ab + tap * 2048 + 512);
#pragma unroll
            for (int pb = 0; pb < 2; ++pb) {
                int slot  = (w + kh) * 68 + lp + pb * 32 + kw;
                int byteo = slot * 40 + ((lk ^ (slot & 1)) << 4);
                short8 bv = *(const short8*)(Bb + byteo);
                acc[0][pb] = __builtin_amdgcn_mfma_f32_32x32x16_bf16(a0, bv, acc[0][pb], 0, 0, 0);
                acc[1][pb] = __builtin_amdgcn_mfma_f32_32x32x16_bf16(a1, bv, acc[1][pb], 0, 0, 0);
            }
        }
        __builtin_amdgcn_s_setprio(0);
    };

    // ---- 4-phase pipeline ----
    issue_w(0); issue_f(0);
    vm0(); bar();
    convert(Xb[0]); bar();
    issue_w(1); issue_f(16);
    compute(Xb[0], Wd[0]);        // phase 0
    vm0(); bar();
    convert(Xb[1]); bar();
    issue_w(2); issue_f(32);
    compute(Xb[1], Wd[1]);        // phase 1
    vm0(); bar();
    convert(Xb[0]); bar();
    issue_w(3); issue_f(48);
    compute(Xb[0], Wd[0]);        // phase 2
    vm0(); bar();
    convert(Xb[1]); bar();
    compute(Xb[1], Wd[1]);        // phase 3

    // ---- epilogue: bias + store (full 128B line segments) ----
    const size_t ob = (size_t)bz * COUT_ * HW_ + (size_t)(y0 + w) * W_ + x0;
#pragma unroll
    for (int cg = 0; cg < 2; ++cg) {
#pragma unroll
        for (int g = 0; g < 16; ++g) {
            int co = cg * 32 + (g & 3) + 8 * (g >> 2) + 4 * lk;
            float bs = bias[co];
            out[ob + (size_t)co * HW_ + lp]      = acc[cg][0][g] + bs;
            out[ob + (size_t)co * HW_ + 32 + lp] = acc[cg][1][g] + bs;
        }
    }
}

extern "C" void kernel_launch(void* const* d_in, const int* in_sizes, int n_in,
                              void* d_out, int out_size, void* d_ws, size_t ws_size,
                              hipStream_t stream) {
    const float* x      = (const float*)d_in[0];
    const float* att    = (const float*)d_in[1];
    const float* weight = (const float*)d_in[2];
    const float* tb     = (const float*)d_in[3];
    const float* tq     = (const float*)d_in[4];
    const float* tn     = (const float*)d_in[5];
    const float* tx     = (const float*)d_in[6];
    const float* mb     = (const float*)d_in[7];
    const float* mq     = (const float*)d_in[8];
    const float* mn     = (const float*)d_in[9];
    const float* mx     = (const float*)d_in[10];
    const float* bias   = (const float*)d_in[11];

    unsigned short* aggb = (unsigned short*)d_ws;   // 590 KB incl. pad
    float* outp = (float*)d_out;

    int n_agg = B_ * 9 * COUT_ * CIN_;
    prep_weights_kernel<<<(n_agg + 255) / 256, 256, 0, stream>>>(
        att, weight, tb, tq, tn, tx, mb, mq, mn, mx, aggb);

    conv_kernel<<<1024, 512, 0, stream>>>(
        x, (const unsigned char*)d_ws, bias, outp);
}